// Round 11
// baseline (567.857 us; speedup 1.0000x reference)
//
#include <hip/hip_runtime.h>

// RGCNConv: out_i = x_i @ W_root + bias + sum_r mean_{j in N_r(i)} x_j @ W_r
//
// R11: intra-block phase-split fusion (aggregate+GEMM in ONE kernel, no 205 MB
// mean HBM round-trip):
//   sort: R10's two-level multisplit -> CSR (unchanged, validated)
//   wallt: WallTc[n][k], k<1024 -> W[k>>7][k&127][n], k>=1024 -> Wroot (root LAST)
//   fused: block owns 128 nodes. For g in {0,1} (rels 4g..4g+3):
//     phase A: 8192 lane-tasks aggregate own nodes' means -> meanslab slice
//              (global, but written+read by the same block/XCD -> cache-hot)
//     phase B: 16 MFMA k-steps staging own slab slice + WallTc window
//   then root phase (xbf @ Wroot window) + bias epilogue. acc lives in regs.

constexpr int D = 128;
constexpr int R = 8;
constexpr int TILE = 2048;

typedef __bf16 bf16x8 __attribute__((ext_vector_type(8)));
typedef float  f32x4  __attribute__((ext_vector_type(4)));
typedef unsigned short u16x8 __attribute__((ext_vector_type(8)));
typedef unsigned short u16x4 __attribute__((ext_vector_type(4)));

__device__ __forceinline__ unsigned short f2bf(float f) {
    unsigned u = __builtin_bit_cast(unsigned, f);
    u += 0x7FFFu + ((u >> 16) & 1u);          // round-to-nearest-even
    return (unsigned short)(u >> 16);
}
__device__ __forceinline__ float bf2f(unsigned short h) {
    return __builtin_bit_cast(float, (unsigned)h << 16);
}

// ---- phase 0: x -> bf16 ----
__global__ __launch_bounds__(256)
void xbf_kernel(const float* __restrict__ x, unsigned short* __restrict__ xbf, int nquad) {
    int stride = gridDim.x * 256;
    for (int i = blockIdx.x * 256 + threadIdx.x; i < nquad; i += stride) {
        float4 v = ((const float4*)x)[i];
        u16x4 o;
        o[0] = f2bf(v.x); o[1] = f2bf(v.y); o[2] = f2bf(v.z); o[3] = f2bf(v.w);
        ((u16x4*)xbf)[i] = o;
    }
}

// ---- sort phase (R10 multisplit, unchanged) ----
__global__ __launch_bounds__(256)
void bcount_kernel(const int* __restrict__ dst, const int* __restrict__ et,
                   int* __restrict__ meta, int E) {
    __shared__ int cnt8[8];
    if (threadIdx.x < 8) cnt8[threadIdx.x] = 0;
    __syncthreads();
    int stride = gridDim.x * 256;
    for (int e = blockIdx.x * 256 + threadIdx.x; e < E; e += stride) {
        int seg = dst[e] * R + et[e];
        atomicAdd(&cnt8[(seg >> 7) & 7], 1);
    }
    __syncthreads();
    if (threadIdx.x < 8) atomicAdd(&meta[threadIdx.x], cnt8[threadIdx.x]);
}

__global__ void bscan_kernel(int* __restrict__ meta) {
    if (threadIdx.x == 0) {
        int cum = 0;
        for (int p = 0; p < 8; ++p) {
            meta[8 + p]  = cum;
            meta[16 + p] = cum;
            cum += meta[p];
        }
    }
}

__global__ __launch_bounds__(256)
void bucketA_kernel(const int* __restrict__ src, const int* __restrict__ dst,
                    const int* __restrict__ et, int* __restrict__ ebuf_seg,
                    int* __restrict__ ebuf_src, int* __restrict__ meta, int E) {
    __shared__ int cntw[4][8];
    __shared__ int basew[4][8];
    const int tid = threadIdx.x;
    const int w   = tid >> 6;
    for (int t0 = blockIdx.x * TILE; t0 < E; t0 += gridDim.x * TILE) {
        if (tid < 32) cntw[tid >> 3][tid & 7] = 0;
        __syncthreads();
        int seg[8], sr[8], pt[8];
        bool ok[8];
        #pragma unroll
        for (int j = 0; j < 8; ++j) {
            int e = t0 + j * 256 + tid;
            ok[j] = e < E;
            if (ok[j]) {
                seg[j] = dst[e] * R + et[e];
                sr[j]  = src[e];
                pt[j]  = (seg[j] >> 7) & 7;
                atomicAdd(&cntw[w][pt[j]], 1);
            }
        }
        __syncthreads();
        if (tid < 8) {
            int p = tid;
            int tot = cntw[0][p] + cntw[1][p] + cntw[2][p] + cntw[3][p];
            int b = atomicAdd(&meta[16 + p], tot);
            basew[0][p] = b;               b += cntw[0][p];
            basew[1][p] = b;               b += cntw[1][p];
            basew[2][p] = b;               b += cntw[2][p];
            basew[3][p] = b;
            cntw[0][p] = 0; cntw[1][p] = 0; cntw[2][p] = 0; cntw[3][p] = 0;
        }
        __syncthreads();
        #pragma unroll
        for (int j = 0; j < 8; ++j) {
            if (ok[j]) {
                int r   = atomicAdd(&cntw[w][pt[j]], 1);
                int pos = basew[w][pt[j]] + r;
                ebuf_seg[pos] = seg[j];
                ebuf_src[pos] = sr[j];
            }
        }
        __syncthreads();
    }
}

__global__ __launch_bounds__(256)
void hist_kernel(const int* __restrict__ ebuf_seg, const int* __restrict__ meta,
                 int* __restrict__ hist) {
    int part = blockIdx.x & 7;
    int nb   = gridDim.x >> 3;
    int lo   = meta[8 + part];
    int n    = meta[part];
    for (int i = (blockIdx.x >> 3) * 256 + threadIdx.x; i < n; i += nb * 256)
        atomicAdd(&hist[ebuf_seg[lo + i]], 1);
}

__global__ __launch_bounds__(256)
void block_sums_kernel(const int* __restrict__ hs, int* __restrict__ bsum, int n) {
    __shared__ int sh[256];
    int i = blockIdx.x * 256 + threadIdx.x;
    sh[threadIdx.x] = (i < n) ? hs[i] : 0;
    __syncthreads();
    for (int off = 128; off > 0; off >>= 1) {
        if (threadIdx.x < off) sh[threadIdx.x] += sh[threadIdx.x + off];
        __syncthreads();
    }
    if (threadIdx.x == 0) bsum[blockIdx.x] = sh[0];
}

__global__ __launch_bounds__(64)
void scan_bsum_kernel(int* __restrict__ bsum, int nb) {
    int lane = threadIdx.x;
    int carry = 0;
    for (int base = 0; base < nb; base += 64) {
        int i = base + lane;
        int orig = (i < nb) ? bsum[i] : 0;
        int v = orig;
        #pragma unroll
        for (int off = 1; off < 64; off <<= 1) {
            int u = __shfl_up(v, off, 64);
            if (lane >= off) v += u;
        }
        int tot = __shfl(v, 63, 64);
        if (i < nb) bsum[i] = carry + (v - orig);
        carry += tot;
    }
}

__global__ __launch_bounds__(256)
void scan_block_kernel(int* __restrict__ hs, const int* __restrict__ bsum,
                       int* __restrict__ cursor, int n, int E) {
    __shared__ int sh[256];
    int tid = threadIdx.x;
    int i = blockIdx.x * 256 + tid;
    int v = (i < n) ? hs[i] : 0;
    sh[tid] = v;
    __syncthreads();
    for (int off = 1; off < 256; off <<= 1) {
        int u = (tid >= off) ? sh[tid - off] : 0;
        __syncthreads();
        sh[tid] += u;
        __syncthreads();
    }
    int st = bsum[blockIdx.x] + sh[tid] - v;
    if (i < n) { hs[i] = st; cursor[i] = st; }
    if (i == n) hs[n] = E;
}

__global__ __launch_bounds__(256)
void bucketB_kernel(const int* __restrict__ ebuf_seg, const int* __restrict__ ebuf_src,
                    const int* __restrict__ meta, int* __restrict__ cursor,
                    int* __restrict__ spack) {
    int part = blockIdx.x & 7;
    int nb   = gridDim.x >> 3;
    int lo   = meta[8 + part];
    int n    = meta[part];
    for (int i = (blockIdx.x >> 3) * 256 + threadIdx.x; i < n; i += nb * 256) {
        int seg = ebuf_seg[lo + i];
        int s   = ebuf_src[lo + i];
        int pos = atomicAdd(&cursor[seg], 1);
        spack[pos] = s;
    }
}

// ---- WallTc[n][k]: k<1024 -> W[k>>7][k&127][n]; k>=1024 -> Wroot[k-1024][n] ----
__global__ __launch_bounds__(256)
void wallt_kernel(const float* __restrict__ Wroot, const float* __restrict__ W,
                  unsigned short* __restrict__ WallTc) {
    int idx = blockIdx.x * 256 + threadIdx.x;
    if (idx >= 128 * 1152) return;
    int n = idx / 1152, k = idx % 1152;
    float v = (k < 1024) ? W[(size_t)(k >> 7) * 16384 + (size_t)(k & 127) * 128 + n]
                         : Wroot[(size_t)(k - 1024) * 128 + n];
    WallTc[idx] = f2bf(v);
}

// ---- fused: per-block phase-split aggregate + MFMA ----
__global__ __launch_bounds__(256)
void fused_kernel(const unsigned short* __restrict__ xbf,
                  const unsigned short* __restrict__ WallTc,
                  const int* __restrict__ spack,
                  const int* __restrict__ hstart,
                  unsigned short* __restrict__ meanslab,   // [N][512] bf16
                  const float* __restrict__ bias,
                  float* __restrict__ out, int N) {
    __shared__ unsigned short As[128][32];
    __shared__ unsigned short Bs[128][32];
    const int tid  = threadIdx.x;
    const int nd0  = blockIdx.x * 128;
    const int lane = tid & 63;
    const int wid  = tid >> 6;
    const int wm   = wid >> 1, wn = wid & 1;
    const int srow = tid >> 1;
    const int sh16 = (tid & 1) * 16;
    const int gnode = nd0 + srow;
    const bool nok  = gnode < N;

    f32x4 acc[4][4] = {};

    for (int g = 0; g < 2; ++g) {
        if (g) __syncthreads();        // phase B of g-1 done before slab overwrite

        // ---- phase A: aggregate rels 4g..4g+3 for own 128 nodes ----
        for (int i = 0; i < 32; ++i) {
            int t  = i * 256 + tid;
            int c8 = t & 15;           // col octet (16 consecutive tids -> 256B run)
            int rl = (t >> 4) & 3;
            int nl = t >> 6;
            int node = nd0 + nl;
            if (node < N) {
                int seg = node * R + g * 4 + rl;
                int p0 = hstart[seg], p1 = hstart[seg + 1];
                int coff = c8 * 8;
                float a[8] = {};
                for (int p = p0; p < p1; p += 4) {
                    int s0 = spack[p];
                    int s1 = (p + 1 < p1) ? spack[p + 1] : -1;
                    int s2 = (p + 2 < p1) ? spack[p + 2] : -1;
                    int s3 = (p + 3 < p1) ? spack[p + 3] : -1;
                    u16x8 v0 = *(const u16x8*)(xbf + ((size_t)s0 << 7) + coff);
                    #pragma unroll
                    for (int j = 0; j < 8; ++j) a[j] += bf2f(v0[j]);
                    if (s1 >= 0) {
                        u16x8 v = *(const u16x8*)(xbf + ((size_t)s1 << 7) + coff);
                        #pragma unroll
                        for (int j = 0; j < 8; ++j) a[j] += bf2f(v[j]);
                    }
                    if (s2 >= 0) {
                        u16x8 v = *(const u16x8*)(xbf + ((size_t)s2 << 7) + coff);
                        #pragma unroll
                        for (int j = 0; j < 8; ++j) a[j] += bf2f(v[j]);
                    }
                    if (s3 >= 0) {
                        u16x8 v = *(const u16x8*)(xbf + ((size_t)s3 << 7) + coff);
                        #pragma unroll
                        for (int j = 0; j < 8; ++j) a[j] += bf2f(v[j]);
                    }
                }
                float inv = (p1 > p0) ? 1.0f / (float)(p1 - p0) : 0.0f;
                u16x8 o;
                #pragma unroll
                for (int j = 0; j < 8; ++j) o[j] = f2bf(a[j] * inv);
                *(u16x8*)(meanslab + ((size_t)node << 9) + rl * 128 + coff) = o;
            }
        }
        __syncthreads();               // slab writes visible to block

        // ---- phase B: 16 MFMA k-steps over this group's 512-k window ----
        for (int kt = 0; kt < 16; ++kt) {
            if (kt) __syncthreads();
            u16x8 a0, a1;
            #pragma unroll
            for (int j = 0; j < 8; ++j) { a0[j] = 0; a1[j] = 0; }
            if (nok) {
                const u16x8* mp = (const u16x8*)(meanslab + ((size_t)gnode << 9)
                                                 + kt * 32 + sh16);
                a0 = mp[0]; a1 = mp[1];
            }
            const u16x8* wp = (const u16x8*)(WallTc + (size_t)srow * 1152
                                             + g * 512 + kt * 32 + sh16);
            u16x8 b0 = wp[0], b1 = wp[1];
            *(u16x8*)&As[srow][sh16]     = a0;
            *(u16x8*)&As[srow][sh16 + 8] = a1;
            *(u16x8*)&Bs[srow][sh16]     = b0;
            *(u16x8*)&Bs[srow][sh16 + 8] = b1;
            __syncthreads();

            const int kg = (lane >> 4) * 8;
            const int rl2 = lane & 15;
            bf16x8 av[4], bv[4];
            #pragma unroll
            for (int f = 0; f < 4; ++f) {
                av[f] = __builtin_bit_cast(bf16x8, *(const u16x8*)&As[wm * 64 + f * 16 + rl2][kg]);
                bv[f] = __builtin_bit_cast(bf16x8, *(const u16x8*)&Bs[wn * 64 + f * 16 + rl2][kg]);
            }
            #pragma unroll
            for (int mf = 0; mf < 4; ++mf)
                #pragma unroll
                for (int nf = 0; nf < 4; ++nf)
                    acc[mf][nf] = __builtin_amdgcn_mfma_f32_16x16x32_bf16(av[mf], bv[nf],
                                                                         acc[mf][nf], 0, 0, 0);
        }
    }

    // ---- root phase: A = xbf rows, B = WallTc k-window 1024.. ----
    for (int kt = 0; kt < 4; ++kt) {
        __syncthreads();
        u16x8 a0, a1;
        #pragma unroll
        for (int j = 0; j < 8; ++j) { a0[j] = 0; a1[j] = 0; }
        if (nok) {
            const u16x8* xp = (const u16x8*)(xbf + ((size_t)gnode << 7) + kt * 32 + sh16);
            a0 = xp[0]; a1 = xp[1];
        }
        const u16x8* wp = (const u16x8*)(WallTc + (size_t)srow * 1152
                                         + 1024 + kt * 32 + sh16);
        u16x8 b0 = wp[0], b1 = wp[1];
        *(u16x8*)&As[srow][sh16]     = a0;
        *(u16x8*)&As[srow][sh16 + 8] = a1;
        *(u16x8*)&Bs[srow][sh16]     = b0;
        *(u16x8*)&Bs[srow][sh16 + 8] = b1;
        __syncthreads();

        const int kg = (lane >> 4) * 8;
        const int rl2 = lane & 15;
        bf16x8 av[4], bv[4];
        #pragma unroll
        for (int f = 0; f < 4; ++f) {
            av[f] = __builtin_bit_cast(bf16x8, *(const u16x8*)&As[wm * 64 + f * 16 + rl2][kg]);
            bv[f] = __builtin_bit_cast(bf16x8, *(const u16x8*)&Bs[wn * 64 + f * 16 + rl2][kg]);
        }
        #pragma unroll
        for (int mf = 0; mf < 4; ++mf)
            #pragma unroll
            for (int nf = 0; nf < 4; ++nf)
                acc[mf][nf] = __builtin_amdgcn_mfma_f32_16x16x32_bf16(av[mf], bv[nf],
                                                                     acc[mf][nf], 0, 0, 0);
    }

    // ---- epilogue ----
    const int rl2 = lane & 15;
    const int rg  = lane >> 4;
    #pragma unroll
    for (int nf = 0; nf < 4; ++nf) {
        int n = wn * 64 + nf * 16 + rl2;
        float bb = bias[n];
        #pragma unroll
        for (int mf = 0; mf < 4; ++mf) {
            #pragma unroll
            for (int i = 0; i < 4; ++i) {
                int nd = nd0 + wm * 64 + mf * 16 + rg * 4 + i;
                if (nd < N) out[(size_t)nd * D + n] = acc[mf][nf][i] + bb;
            }
        }
    }
}

extern "C" void kernel_launch(void* const* d_in, const int* in_sizes, int n_in,
                              void* d_out, int out_size, void* d_ws, size_t ws_size,
                              hipStream_t stream) {
    const float* x     = (const float*)d_in[0];
    const float* W     = (const float*)d_in[1];
    const float* Wroot = (const float*)d_in[2];
    const float* bias  = (const float*)d_in[3];
    const int*   ei    = (const int*)d_in[4];
    const int*   et    = (const int*)d_in[5];
    float*       out   = (float*)d_out;

    const int N = in_sizes[0] / D;
    const int E = in_sizes[5];
    const int* src = ei;
    const int* dst = ei + E;

    const int NSEG = N * R;
    const int NB   = (NSEG + 256) / 256;

    const size_t slab_bytes   = (size_t)N * 512 * 2;      // 102.4 MB
    const size_t xbf_bytes    = (size_t)N * D * 2;        // 25.6 MB
    const size_t walltc_bytes = (size_t)128 * 1152 * 2;
    const size_t need = slab_bytes + xbf_bytes + walltc_bytes +
                        ((size_t)(NSEG + 1) + NSEG + E + NB + 32) * 4 + 256;
    if (ws_size < need) return;

    char* p = (char*)d_ws;
    unsigned short* meanslab = (unsigned short*)p;  p += slab_bytes;
    unsigned short* xbf      = (unsigned short*)p;  p += xbf_bytes;
    unsigned short* WallTc   = (unsigned short*)p;  p += walltc_bytes;
    int* hstart = (int*)p;  p += (size_t)(NSEG + 1) * 4;
    int* cursor = (int*)p;  p += (size_t)NSEG * 4;
    int* spack  = (int*)p;  p += (size_t)E * 4;
    int* bsum   = (int*)p;  p += (size_t)NB * 4;
    int* meta   = (int*)p;

    // ebuf aliases meanslab (dead before fused_kernel runs)
    int* ebuf_seg = (int*)meanslab;
    int* ebuf_src = ebuf_seg + E;

    hipMemsetAsync(hstart, 0, (size_t)(NSEG + 1) * 4, stream);
    hipMemsetAsync(meta, 0, 32 * 4, stream);

    xbf_kernel<<<2048, 256, 0, stream>>>(x, xbf, N * D / 4);
    wallt_kernel<<<(128 * 1152 + 255) / 256, 256, 0, stream>>>(Wroot, W, WallTc);

    bcount_kernel<<<1024, 256, 0, stream>>>(dst, et, meta, E);
    bscan_kernel<<<1, 64, 0, stream>>>(meta);
    bucketA_kernel<<<(E + TILE - 1) / TILE, 256, 0, stream>>>(
        src, dst, et, ebuf_seg, ebuf_src, meta, E);
    hist_kernel<<<768, 256, 0, stream>>>(ebuf_seg, meta, hstart);
    block_sums_kernel<<<NB, 256, 0, stream>>>(hstart, bsum, NSEG);
    scan_bsum_kernel<<<1, 64, 0, stream>>>(bsum, NB);
    scan_block_kernel<<<NB, 256, 0, stream>>>(hstart, bsum, cursor, NSEG, E);
    bucketB_kernel<<<768, 256, 0, stream>>>(ebuf_seg, ebuf_src, meta, cursor, spack);

    const int gx = (N + 127) / 128;
    fused_kernel<<<gx, 256, 0, stream>>>(xbf, WallTc, spack, hstart, meanslab,
                                         bias, out, N);
}

// Round 12
// 566.194 us; speedup vs baseline: 1.0029x; 1.0029x over previous
//
#include <hip/hip_runtime.h>

// RGCNConv: out_i = x_i @ W_root + bias + sum_r mean_{j in N_r(i)} x_j @ W_r
//
// R12: LDS-RESIDENT fused aggregate+MFMA (mean never touches global memory):
//   sort: R10 two-level multisplit -> CSR (unchanged)
//   wallt: WallTc[n][k], k<1024 -> W[k>>7][k&127][n]; k>=1024 -> Wroot
//   fused: block owns 128 nodes. For rp in 0..7:
//     phase A: 2048 tasks aggregate rel rp means -> Am[128][128] bf16 in LDS
//              (XOR-swizzled rows; node>=N rows written as zeros)
//     phase B: 4 MFMA k-steps, A-fragments read DIRECTLY from Am,
//              B staged per-k (8 KB) from L2-resident WallTc
//   root phase: stage xbf rows into Am, 4 k-steps; epilogue +bias, store out.
//   LDS = 32+8 = 40 KB -> 4 blocks/CU. No mean buffer anywhere.

constexpr int D = 128;
constexpr int R = 8;
constexpr int TILE = 2048;

typedef __bf16 bf16x8 __attribute__((ext_vector_type(8)));
typedef float  f32x4  __attribute__((ext_vector_type(4)));
typedef unsigned short u16x8 __attribute__((ext_vector_type(8)));
typedef unsigned short u16x4 __attribute__((ext_vector_type(4)));

__device__ __forceinline__ unsigned short f2bf(float f) {
    unsigned u = __builtin_bit_cast(unsigned, f);
    u += 0x7FFFu + ((u >> 16) & 1u);          // round-to-nearest-even
    return (unsigned short)(u >> 16);
}
__device__ __forceinline__ float bf2f(unsigned short h) {
    return __builtin_bit_cast(float, (unsigned)h << 16);
}

// ---- phase 0: x -> bf16 ----
__global__ __launch_bounds__(256)
void xbf_kernel(const float* __restrict__ x, unsigned short* __restrict__ xbf, int nquad) {
    int stride = gridDim.x * 256;
    for (int i = blockIdx.x * 256 + threadIdx.x; i < nquad; i += stride) {
        float4 v = ((const float4*)x)[i];
        u16x4 o;
        o[0] = f2bf(v.x); o[1] = f2bf(v.y); o[2] = f2bf(v.z); o[3] = f2bf(v.w);
        ((u16x4*)xbf)[i] = o;
    }
}

// ---- sort phase (R10 multisplit, unchanged) ----
__global__ __launch_bounds__(256)
void bcount_kernel(const int* __restrict__ dst, const int* __restrict__ et,
                   int* __restrict__ meta, int E) {
    __shared__ int cnt8[8];
    if (threadIdx.x < 8) cnt8[threadIdx.x] = 0;
    __syncthreads();
    int stride = gridDim.x * 256;
    for (int e = blockIdx.x * 256 + threadIdx.x; e < E; e += stride) {
        int seg = dst[e] * R + et[e];
        atomicAdd(&cnt8[(seg >> 7) & 7], 1);
    }
    __syncthreads();
    if (threadIdx.x < 8) atomicAdd(&meta[threadIdx.x], cnt8[threadIdx.x]);
}

__global__ void bscan_kernel(int* __restrict__ meta) {
    if (threadIdx.x == 0) {
        int cum = 0;
        for (int p = 0; p < 8; ++p) {
            meta[8 + p]  = cum;
            meta[16 + p] = cum;
            cum += meta[p];
        }
    }
}

__global__ __launch_bounds__(256)
void bucketA_kernel(const int* __restrict__ src, const int* __restrict__ dst,
                    const int* __restrict__ et, int* __restrict__ ebuf_seg,
                    int* __restrict__ ebuf_src, int* __restrict__ meta, int E) {
    __shared__ int cntw[4][8];
    __shared__ int basew[4][8];
    const int tid = threadIdx.x;
    const int w   = tid >> 6;
    for (int t0 = blockIdx.x * TILE; t0 < E; t0 += gridDim.x * TILE) {
        if (tid < 32) cntw[tid >> 3][tid & 7] = 0;
        __syncthreads();
        int seg[8], sr[8], pt[8];
        bool ok[8];
        #pragma unroll
        for (int j = 0; j < 8; ++j) {
            int e = t0 + j * 256 + tid;
            ok[j] = e < E;
            if (ok[j]) {
                seg[j] = dst[e] * R + et[e];
                sr[j]  = src[e];
                pt[j]  = (seg[j] >> 7) & 7;
                atomicAdd(&cntw[w][pt[j]], 1);
            }
        }
        __syncthreads();
        if (tid < 8) {
            int p = tid;
            int tot = cntw[0][p] + cntw[1][p] + cntw[2][p] + cntw[3][p];
            int b = atomicAdd(&meta[16 + p], tot);
            basew[0][p] = b;               b += cntw[0][p];
            basew[1][p] = b;               b += cntw[1][p];
            basew[2][p] = b;               b += cntw[2][p];
            basew[3][p] = b;
            cntw[0][p] = 0; cntw[1][p] = 0; cntw[2][p] = 0; cntw[3][p] = 0;
        }
        __syncthreads();
        #pragma unroll
        for (int j = 0; j < 8; ++j) {
            if (ok[j]) {
                int r   = atomicAdd(&cntw[w][pt[j]], 1);
                int pos = basew[w][pt[j]] + r;
                ebuf_seg[pos] = seg[j];
                ebuf_src[pos] = sr[j];
            }
        }
        __syncthreads();
    }
}

__global__ __launch_bounds__(256)
void hist_kernel(const int* __restrict__ ebuf_seg, const int* __restrict__ meta,
                 int* __restrict__ hist) {
    int part = blockIdx.x & 7;
    int nb   = gridDim.x >> 3;
    int lo   = meta[8 + part];
    int n    = meta[part];
    for (int i = (blockIdx.x >> 3) * 256 + threadIdx.x; i < n; i += nb * 256)
        atomicAdd(&hist[ebuf_seg[lo + i]], 1);
}

__global__ __launch_bounds__(256)
void block_sums_kernel(const int* __restrict__ hs, int* __restrict__ bsum, int n) {
    __shared__ int sh[256];
    int i = blockIdx.x * 256 + threadIdx.x;
    sh[threadIdx.x] = (i < n) ? hs[i] : 0;
    __syncthreads();
    for (int off = 128; off > 0; off >>= 1) {
        if (threadIdx.x < off) sh[threadIdx.x] += sh[threadIdx.x + off];
        __syncthreads();
    }
    if (threadIdx.x == 0) bsum[blockIdx.x] = sh[0];
}

__global__ __launch_bounds__(64)
void scan_bsum_kernel(int* __restrict__ bsum, int nb) {
    int lane = threadIdx.x;
    int carry = 0;
    for (int base = 0; base < nb; base += 64) {
        int i = base + lane;
        int orig = (i < nb) ? bsum[i] : 0;
        int v = orig;
        #pragma unroll
        for (int off = 1; off < 64; off <<= 1) {
            int u = __shfl_up(v, off, 64);
            if (lane >= off) v += u;
        }
        int tot = __shfl(v, 63, 64);
        if (i < nb) bsum[i] = carry + (v - orig);
        carry += tot;
    }
}

__global__ __launch_bounds__(256)
void scan_block_kernel(int* __restrict__ hs, const int* __restrict__ bsum,
                       int* __restrict__ cursor, int n, int E) {
    __shared__ int sh[256];
    int tid = threadIdx.x;
    int i = blockIdx.x * 256 + tid;
    int v = (i < n) ? hs[i] : 0;
    sh[tid] = v;
    __syncthreads();
    for (int off = 1; off < 256; off <<= 1) {
        int u = (tid >= off) ? sh[tid - off] : 0;
        __syncthreads();
        sh[tid] += u;
        __syncthreads();
    }
    int st = bsum[blockIdx.x] + sh[tid] - v;
    if (i < n) { hs[i] = st; cursor[i] = st; }
    if (i == n) hs[n] = E;
}

__global__ __launch_bounds__(256)
void bucketB_kernel(const int* __restrict__ ebuf_seg, const int* __restrict__ ebuf_src,
                    const int* __restrict__ meta, int* __restrict__ cursor,
                    int* __restrict__ spack) {
    int part = blockIdx.x & 7;
    int nb   = gridDim.x >> 3;
    int lo   = meta[8 + part];
    int n    = meta[part];
    for (int i = (blockIdx.x >> 3) * 256 + threadIdx.x; i < n; i += nb * 256) {
        int seg = ebuf_seg[lo + i];
        int s   = ebuf_src[lo + i];
        int pos = atomicAdd(&cursor[seg], 1);
        spack[pos] = s;
    }
}

// ---- WallTc[n][k]: k<1024 -> W[k>>7][k&127][n]; k>=1024 -> Wroot[k-1024][n] ----
__global__ __launch_bounds__(256)
void wallt_kernel(const float* __restrict__ Wroot, const float* __restrict__ W,
                  unsigned short* __restrict__ WallTc) {
    int idx = blockIdx.x * 256 + threadIdx.x;
    if (idx >= 128 * 1152) return;
    int n = idx / 1152, k = idx % 1152;
    float v = (k < 1024) ? W[(size_t)(k >> 7) * 16384 + (size_t)(k & 127) * 128 + n]
                         : Wroot[(size_t)(k - 1024) * 128 + n];
    WallTc[idx] = f2bf(v);
}

// ---- fused: LDS-resident per-relation aggregate + MFMA ----
__global__ __launch_bounds__(256)
void fused_kernel(const unsigned short* __restrict__ xbf,
                  const unsigned short* __restrict__ WallTc,
                  const int* __restrict__ spack,
                  const int* __restrict__ hstart,
                  const float* __restrict__ bias,
                  float* __restrict__ out, int N) {
    __shared__ unsigned short Am[128 * 128];   // 32 KB, XOR-swizzled rows (256B each)
    __shared__ unsigned short Bsh[128 * 32];   // 8 KB per-kstep B staging

    const int tid  = threadIdx.x;
    const int nd0  = blockIdx.x * 128;
    const int lane = tid & 63;
    const int wid  = tid >> 6;
    const int wm   = wid >> 1, wn = wid & 1;   // wave 2x2, 64x64 each
    const int srow = tid >> 1;
    const int half = tid & 1;
    const int sh16 = half * 16;                // element offset for B staging
    const int rl2  = lane & 15;
    const int kb   = (lane >> 4) * 16;         // byte offset of k-octet

    f32x4 acc[4][4] = {};

    for (int rp = 0; rp < 9; ++rp) {
        // ---- phase A: fill Am ----
        if (rp < 8) {
            #pragma unroll
            for (int i = 0; i < 8; ++i) {
                int t  = i * 256 + tid;        // 0..2047
                int nl = t >> 4;               // node-local 0..127
                int c8 = t & 15;               // col octet
                int node = nd0 + nl;
                float a[8] = {};
                int cnt = 0;
                if (node < N) {
                    int seg = node * R + rp;
                    int p0 = hstart[seg], p1 = hstart[seg + 1];
                    cnt = p1 - p0;
                    int coff = c8 * 8;
                    for (int p = p0; p < p1; p += 4) {
                        int s0 = spack[p];
                        int s1 = (p + 1 < p1) ? spack[p + 1] : -1;
                        int s2 = (p + 2 < p1) ? spack[p + 2] : -1;
                        int s3 = (p + 3 < p1) ? spack[p + 3] : -1;
                        u16x8 v0 = *(const u16x8*)(xbf + ((size_t)s0 << 7) + coff);
                        #pragma unroll
                        for (int j = 0; j < 8; ++j) a[j] += bf2f(v0[j]);
                        if (s1 >= 0) {
                            u16x8 v = *(const u16x8*)(xbf + ((size_t)s1 << 7) + coff);
                            #pragma unroll
                            for (int j = 0; j < 8; ++j) a[j] += bf2f(v[j]);
                        }
                        if (s2 >= 0) {
                            u16x8 v = *(const u16x8*)(xbf + ((size_t)s2 << 7) + coff);
                            #pragma unroll
                            for (int j = 0; j < 8; ++j) a[j] += bf2f(v[j]);
                        }
                        if (s3 >= 0) {
                            u16x8 v = *(const u16x8*)(xbf + ((size_t)s3 << 7) + coff);
                            #pragma unroll
                            for (int j = 0; j < 8; ++j) a[j] += bf2f(v[j]);
                        }
                    }
                }
                float inv = (cnt > 0) ? 1.0f / (float)cnt : 0.0f;
                u16x8 o;
                #pragma unroll
                for (int j = 0; j < 8; ++j) o[j] = f2bf(a[j] * inv);
                // always write (zeros for node>=N): MFMA reads all 128 rows
                *(u16x8*)((char*)Am + nl * 256 + ((c8 * 16) ^ ((nl & 7) << 4))) = o;
            }
        } else {
            // root phase: stage xbf rows into Am (2 threads per row, 128B each)
            int node = nd0 + srow;
            unsigned swz = (srow & 7) << 4;
            #pragma unroll
            for (int j = 0; j < 8; ++j) {
                u16x8 v;
                #pragma unroll
                for (int q = 0; q < 8; ++q) v[q] = 0;
                if (node < N)
                    v = *(const u16x8*)(xbf + ((size_t)node << 7) + half * 64 + j * 8);
                *(u16x8*)((char*)Am + srow * 256 + ((half * 128 + j * 16) ^ swz)) = v;
            }
        }
        __syncthreads();   // Am ready

        // ---- phase B: 4 MFMA k-steps over rp's 128-col window ----
        #pragma unroll
        for (int kt = 0; kt < 4; ++kt) {
            // stage B k-tile (Bsh last read before the trailing sync below)
            const u16x8* wp = (const u16x8*)(WallTc + (size_t)srow * 1152
                                             + rp * 128 + kt * 32 + sh16);
            u16x8 b0 = wp[0], b1 = wp[1];
            *(u16x8*)&Bsh[srow * 32 + sh16]     = b0;
            *(u16x8*)&Bsh[srow * 32 + sh16 + 8] = b1;
            __syncthreads();

            bf16x8 av[4], bv[4];
            #pragma unroll
            for (int f = 0; f < 4; ++f) {
                int ar = wm * 64 + f * 16 + rl2;
                av[f] = __builtin_bit_cast(bf16x8,
                    *(const u16x8*)((const char*)Am + ar * 256
                                    + ((kt * 64 + kb) ^ ((ar & 7) << 4))));
                int br = wn * 64 + f * 16 + rl2;
                bv[f] = __builtin_bit_cast(bf16x8,
                    *(const u16x8*)((const char*)Bsh + br * 64 + kb));
            }
            #pragma unroll
            for (int mf = 0; mf < 4; ++mf)
                #pragma unroll
                for (int nf = 0; nf < 4; ++nf)
                    acc[mf][nf] = __builtin_amdgcn_mfma_f32_16x16x32_bf16(av[mf], bv[nf],
                                                                         acc[mf][nf], 0, 0, 0);
            __syncthreads();   // MFMA reads done before next Bsh/Am overwrite
        }
    }

    // ---- epilogue: + bias, single store ----
    const int rg = lane >> 4;
    #pragma unroll
    for (int nf = 0; nf < 4; ++nf) {
        int n = wn * 64 + nf * 16 + rl2;
        float bb = bias[n];
        #pragma unroll
        for (int mf = 0; mf < 4; ++mf) {
            #pragma unroll
            for (int i = 0; i < 4; ++i) {
                int nd = nd0 + wm * 64 + mf * 16 + rg * 4 + i;
                if (nd < N) out[(size_t)nd * D + n] = acc[mf][nf][i] + bb;
            }
        }
    }
}

extern "C" void kernel_launch(void* const* d_in, const int* in_sizes, int n_in,
                              void* d_out, int out_size, void* d_ws, size_t ws_size,
                              hipStream_t stream) {
    const float* x     = (const float*)d_in[0];
    const float* W     = (const float*)d_in[1];
    const float* Wroot = (const float*)d_in[2];
    const float* bias  = (const float*)d_in[3];
    const int*   ei    = (const int*)d_in[4];
    const int*   et    = (const int*)d_in[5];
    float*       out   = (float*)d_out;

    const int N = in_sizes[0] / D;
    const int E = in_sizes[5];
    const int* src = ei;
    const int* dst = ei + E;

    const int NSEG = N * R;
    const int NB   = (NSEG + 256) / 256;

    const size_t xbf_bytes    = (size_t)N * D * 2;
    const size_t walltc_bytes = (size_t)128 * 1152 * 2;
    const size_t need = xbf_bytes + walltc_bytes +
                        ((size_t)(NSEG + 1) + NSEG + E + NB + 32 + 2 * (size_t)E) * 4 + 256;
    if (ws_size < need) return;

    char* p = (char*)d_ws;
    unsigned short* xbf    = (unsigned short*)p;  p += xbf_bytes;
    unsigned short* WallTc = (unsigned short*)p;  p += walltc_bytes;
    int* hstart   = (int*)p;  p += (size_t)(NSEG + 1) * 4;
    int* cursor   = (int*)p;  p += (size_t)NSEG * 4;
    int* spack    = (int*)p;  p += (size_t)E * 4;
    int* bsum     = (int*)p;  p += (size_t)NB * 4;
    int* meta     = (int*)p;  p += 32 * 4;
    int* ebuf_seg = (int*)p;  p += (size_t)E * 4;
    int* ebuf_src = (int*)p;

    hipMemsetAsync(hstart, 0, (size_t)(NSEG + 1) * 4, stream);
    hipMemsetAsync(meta, 0, 32 * 4, stream);

    xbf_kernel<<<2048, 256, 0, stream>>>(x, xbf, N * D / 4);
    wallt_kernel<<<(128 * 1152 + 255) / 256, 256, 0, stream>>>(Wroot, W, WallTc);

    bcount_kernel<<<1024, 256, 0, stream>>>(dst, et, meta, E);
    bscan_kernel<<<1, 64, 0, stream>>>(meta);
    bucketA_kernel<<<(E + TILE - 1) / TILE, 256, 0, stream>>>(
        src, dst, et, ebuf_seg, ebuf_src, meta, E);
    hist_kernel<<<768, 256, 0, stream>>>(ebuf_seg, meta, hstart);
    block_sums_kernel<<<NB, 256, 0, stream>>>(hstart, bsum, NSEG);
    scan_bsum_kernel<<<1, 64, 0, stream>>>(bsum, NB);
    scan_block_kernel<<<NB, 256, 0, stream>>>(hstart, bsum, cursor, NSEG, E);
    bucketB_kernel<<<768, 256, 0, stream>>>(ebuf_seg, ebuf_src, meta, cursor, spack);

    const int gx = (N + 127) / 128;
    fused_kernel<<<gx, 256, 0, stream>>>(xbf, WallTc, spack, hstart, bias, out, N);
}

// Round 13
// 416.561 us; speedup vs baseline: 1.3632x; 1.3592x over previous
//
#include <hip/hip_runtime.h>

// RGCNConv: out_i = x_i @ W_root + bias + sum_r mean_{j in N_r(i)} x_j @ W_r
//
// R13 = R10 pipeline with measured defects fixed (fusion abandoned: R7/R11/R12
// all latency-bound at ~345+ us):
//   - CW=64 forced, NO nontemporal store: {xbf 25.6 + mean 102 + spack 6.4} MB
//     fits L3 -> gather L3-hot, gemm reads mean from L3 (R10: streamed from HBM)
//   - GEMM: BM=64 (1563 blocks = 6/CU) + 80B LDS row stride -> conflict-free
//     fragment reads (R10 had 7.2M bank conflicts from 64B stride)
//   - hist folded into bcount (one less pass over edge data)

constexpr int D = 128;
constexpr int R = 8;
constexpr int TILE = 2048;
constexpr int CW = 64;          // feature chunk (2 passes)
constexpr int LDA = 40;         // LDS row stride in elems (80B) - bank-conflict-free

typedef __bf16 bf16x8 __attribute__((ext_vector_type(8)));
typedef float  f32x4  __attribute__((ext_vector_type(4)));
typedef unsigned short u16x8 __attribute__((ext_vector_type(8)));
typedef unsigned short u16x4 __attribute__((ext_vector_type(4)));

__device__ __forceinline__ unsigned short f2bf(float f) {
    unsigned u = __builtin_bit_cast(unsigned, f);
    u += 0x7FFFu + ((u >> 16) & 1u);
    return (unsigned short)(u >> 16);
}
__device__ __forceinline__ float bf2f(unsigned short h) {
    return __builtin_bit_cast(float, (unsigned)h << 16);
}

// ---- x -> bf16 ----
__global__ __launch_bounds__(256)
void xbf_kernel(const float* __restrict__ x, unsigned short* __restrict__ xbf, int nquad) {
    int stride = gridDim.x * 256;
    for (int i = blockIdx.x * 256 + threadIdx.x; i < nquad; i += stride) {
        float4 v = ((const float4*)x)[i];
        u16x4 o;
        o[0] = f2bf(v.x); o[1] = f2bf(v.y); o[2] = f2bf(v.z); o[3] = f2bf(v.w);
        ((u16x4*)xbf)[i] = o;
    }
}

// ---- bcount + seg histogram (fused) ----
__global__ __launch_bounds__(256)
void bcount_kernel(const int* __restrict__ dst, const int* __restrict__ et,
                   int* __restrict__ meta, int* __restrict__ hist, int E) {
    __shared__ int cnt8[8];
    if (threadIdx.x < 8) cnt8[threadIdx.x] = 0;
    __syncthreads();
    int stride = gridDim.x * 256;
    for (int e = blockIdx.x * 256 + threadIdx.x; e < E; e += stride) {
        int seg = dst[e] * R + et[e];
        atomicAdd(&cnt8[(seg >> 7) & 7], 1);
        atomicAdd(&hist[seg], 1);
    }
    __syncthreads();
    if (threadIdx.x < 8) atomicAdd(&meta[threadIdx.x], cnt8[threadIdx.x]);
}

__global__ void bscan_kernel(int* __restrict__ meta) {
    if (threadIdx.x == 0) {
        int cum = 0;
        for (int p = 0; p < 8; ++p) {
            meta[8 + p]  = cum;
            meta[16 + p] = cum;
            cum += meta[p];
        }
    }
}

__global__ __launch_bounds__(256)
void bucketA_kernel(const int* __restrict__ src, const int* __restrict__ dst,
                    const int* __restrict__ et, int* __restrict__ ebuf_seg,
                    int* __restrict__ ebuf_src, int* __restrict__ meta, int E) {
    __shared__ int cntw[4][8];
    __shared__ int basew[4][8];
    const int tid = threadIdx.x;
    const int w   = tid >> 6;
    for (int t0 = blockIdx.x * TILE; t0 < E; t0 += gridDim.x * TILE) {
        if (tid < 32) cntw[tid >> 3][tid & 7] = 0;
        __syncthreads();
        int seg[8], sr[8], pt[8];
        bool ok[8];
        #pragma unroll
        for (int j = 0; j < 8; ++j) {
            int e = t0 + j * 256 + tid;
            ok[j] = e < E;
            if (ok[j]) {
                seg[j] = dst[e] * R + et[e];
                sr[j]  = src[e];
                pt[j]  = (seg[j] >> 7) & 7;
                atomicAdd(&cntw[w][pt[j]], 1);
            }
        }
        __syncthreads();
        if (tid < 8) {
            int p = tid;
            int tot = cntw[0][p] + cntw[1][p] + cntw[2][p] + cntw[3][p];
            int b = atomicAdd(&meta[16 + p], tot);
            basew[0][p] = b;               b += cntw[0][p];
            basew[1][p] = b;               b += cntw[1][p];
            basew[2][p] = b;               b += cntw[2][p];
            basew[3][p] = b;
            cntw[0][p] = 0; cntw[1][p] = 0; cntw[2][p] = 0; cntw[3][p] = 0;
        }
        __syncthreads();
        #pragma unroll
        for (int j = 0; j < 8; ++j) {
            if (ok[j]) {
                int r   = atomicAdd(&cntw[w][pt[j]], 1);
                int pos = basew[w][pt[j]] + r;
                ebuf_seg[pos] = seg[j];
                ebuf_src[pos] = sr[j];
            }
        }
        __syncthreads();
    }
}

__global__ __launch_bounds__(256)
void block_sums_kernel(const int* __restrict__ hs, int* __restrict__ bsum, int n) {
    __shared__ int sh[256];
    int i = blockIdx.x * 256 + threadIdx.x;
    sh[threadIdx.x] = (i < n) ? hs[i] : 0;
    __syncthreads();
    for (int off = 128; off > 0; off >>= 1) {
        if (threadIdx.x < off) sh[threadIdx.x] += sh[threadIdx.x + off];
        __syncthreads();
    }
    if (threadIdx.x == 0) bsum[blockIdx.x] = sh[0];
}

__global__ __launch_bounds__(64)
void scan_bsum_kernel(int* __restrict__ bsum, int nb) {
    int lane = threadIdx.x;
    int carry = 0;
    for (int base = 0; base < nb; base += 64) {
        int i = base + lane;
        int orig = (i < nb) ? bsum[i] : 0;
        int v = orig;
        #pragma unroll
        for (int off = 1; off < 64; off <<= 1) {
            int u = __shfl_up(v, off, 64);
            if (lane >= off) v += u;
        }
        int tot = __shfl(v, 63, 64);
        if (i < nb) bsum[i] = carry + (v - orig);
        carry += tot;
    }
}

__global__ __launch_bounds__(256)
void scan_block_kernel(int* __restrict__ hs, const int* __restrict__ bsum,
                       int* __restrict__ cursor, int n, int E) {
    __shared__ int sh[256];
    int tid = threadIdx.x;
    int i = blockIdx.x * 256 + tid;
    int v = (i < n) ? hs[i] : 0;
    sh[tid] = v;
    __syncthreads();
    for (int off = 1; off < 256; off <<= 1) {
        int u = (tid >= off) ? sh[tid - off] : 0;
        __syncthreads();
        sh[tid] += u;
        __syncthreads();
    }
    int st = bsum[blockIdx.x] + sh[tid] - v;
    if (i < n) { hs[i] = st; cursor[i] = st; }
    if (i == n) hs[n] = E;
}

__global__ __launch_bounds__(256)
void bucketB_kernel(const int* __restrict__ ebuf_seg, const int* __restrict__ ebuf_src,
                    const int* __restrict__ meta, int* __restrict__ cursor,
                    int* __restrict__ spack) {
    int part = blockIdx.x & 7;
    int nb   = gridDim.x >> 3;
    int lo   = meta[8 + part];
    int n    = meta[part];
    for (int i = (blockIdx.x >> 3) * 256 + threadIdx.x; i < n; i += nb * 256) {
        int seg = ebuf_seg[lo + i];
        int s   = ebuf_src[lo + i];
        int pos = atomicAdd(&cursor[seg], 1);
        spack[pos] = s;
    }
}

// ---- aggregate: mean[seg][64] for cols [c0, c0+64), regular stores ----
__global__ __launch_bounds__(256)
void aggregate_kernel(const unsigned short* __restrict__ xbf,
                      const int* __restrict__ spack,
                      const int* __restrict__ hstart,
                      unsigned short* __restrict__ mean,
                      int nseg, int c0) {
    int idx = blockIdx.x * 256 + threadIdx.x;
    int seg = idx >> 3;
    int c8  = idx & 7;
    if (seg >= nseg) return;
    int p0 = hstart[seg], p1 = hstart[seg + 1];
    int coff = c0 + c8 * 8;
    float a[8] = {};
    for (int p = p0; p < p1; p += 4) {
        int s0 = spack[p];
        int s1 = (p + 1 < p1) ? spack[p + 1] : -1;
        int s2 = (p + 2 < p1) ? spack[p + 2] : -1;
        int s3 = (p + 3 < p1) ? spack[p + 3] : -1;
        u16x8 v0 = *(const u16x8*)(xbf + ((size_t)s0 << 7) + coff);
        #pragma unroll
        for (int j = 0; j < 8; ++j) a[j] += bf2f(v0[j]);
        if (s1 >= 0) {
            u16x8 v = *(const u16x8*)(xbf + ((size_t)s1 << 7) + coff);
            #pragma unroll
            for (int j = 0; j < 8; ++j) a[j] += bf2f(v[j]);
        }
        if (s2 >= 0) {
            u16x8 v = *(const u16x8*)(xbf + ((size_t)s2 << 7) + coff);
            #pragma unroll
            for (int j = 0; j < 8; ++j) a[j] += bf2f(v[j]);
        }
        if (s3 >= 0) {
            u16x8 v = *(const u16x8*)(xbf + ((size_t)s3 << 7) + coff);
            #pragma unroll
            for (int j = 0; j < 8; ++j) a[j] += bf2f(v[j]);
        }
    }
    float inv = (p1 > p0) ? 1.0f / (float)(p1 - p0) : 0.0f;
    u16x8 o;
    #pragma unroll
    for (int j = 0; j < 8; ++j) o[j] = f2bf(a[j] * inv);
    *(u16x8*)(mean + ((size_t)seg << 6) + c8 * 8) = o;
}

// ---- WallTc[n][kk] bf16 for one pass ----
__global__ __launch_bounds__(256)
void wallt_kernel(const float* __restrict__ Wroot, const float* __restrict__ W,
                  unsigned short* __restrict__ WallTc, int KW, int c0, int first) {
    int idx = blockIdx.x * 256 + threadIdx.x;
    if (idx >= 128 * KW) return;
    int n = idx / KW, kk = idx % KW;
    float v;
    if (first && kk < 128) {
        v = Wroot[kk * 128 + n];
    } else {
        int lk = kk - (first ? 128 : 0);
        int r = lk / CW, cc = lk % CW;
        v = W[((size_t)r * 128 + c0 + cc) * 128 + n];
    }
    WallTc[idx] = f2bf(v);
}

// ---- MFMA GEMM: BM=64 rows/block, conflict-free 80B-stride LDS ----
template<bool FIRST>
__global__ __launch_bounds__(256)
void mfma_gemm_kernel(const unsigned short* __restrict__ xbf,
                      const unsigned short* __restrict__ mean,
                      const unsigned short* __restrict__ WallTc,
                      const float* __restrict__ bias,
                      float* __restrict__ out,
                      int N, int NT, int KW, int MROW) {
    __shared__ unsigned short As[64 * LDA];    //  5.1 KB
    __shared__ unsigned short Bs[128 * LDA];   // 10.2 KB
    const int tid  = threadIdx.x;
    const int nd0  = blockIdx.x * 64;
    const int lane = tid & 63;
    const int wid  = tid >> 6;
    const int wm   = wid >> 1;         // 2x2 waves: 32 rows x 64 cols each
    const int wn   = wid & 1;
    const int arow = tid >> 2;         // A stage: row 0..63
    const int aoct = tid & 3;          // A stage: octet 0..3
    const int brow = tid >> 1;         // B stage: row 0..127
    const int bhalf = tid & 1;         // B stage: octets 2h, 2h+1

    f32x4 acc[2][4] = {};

    const int  anode = nd0 + arow;
    const bool aok   = anode < N;

    for (int kt = 0; kt < NT; ++kt) {
        if (kt) __syncthreads();
        // A: 1 octet per thread
        u16x8 av8;
        #pragma unroll
        for (int j = 0; j < 8; ++j) av8[j] = 0;
        if (aok) {
            if (FIRST && kt < 4)
                av8 = *(const u16x8*)(xbf + ((size_t)anode << 7) + kt * 32 + aoct * 8);
            else
                av8 = *(const u16x8*)(mean + (size_t)anode * MROW
                                      + (kt - (FIRST ? 4 : 0)) * 32 + aoct * 8);
        }
        // B: 2 octets per thread
        const u16x8* wp = (const u16x8*)(WallTc + (size_t)brow * KW + kt * 32 + bhalf * 16);
        u16x8 b0 = wp[0], b1 = wp[1];

        *(u16x8*)&As[arow * LDA + aoct * 8]            = av8;
        *(u16x8*)&Bs[brow * LDA + bhalf * 16]          = b0;
        *(u16x8*)&Bs[brow * LDA + bhalf * 16 + 8]      = b1;
        __syncthreads();

        const int ko = (lane >> 4) * 8;    // k-octet elem offset
        const int rl = lane & 15;
        bf16x8 af[2], bf[4];
        #pragma unroll
        for (int f = 0; f < 2; ++f)
            af[f] = __builtin_bit_cast(bf16x8,
                *(const u16x8*)&As[(wm * 32 + f * 16 + rl) * LDA + ko]);
        #pragma unroll
        for (int f = 0; f < 4; ++f)
            bf[f] = __builtin_bit_cast(bf16x8,
                *(const u16x8*)&Bs[(wn * 64 + f * 16 + rl) * LDA + ko]);
        #pragma unroll
        for (int mf = 0; mf < 2; ++mf)
            #pragma unroll
            for (int nf = 0; nf < 4; ++nf)
                acc[mf][nf] = __builtin_amdgcn_mfma_f32_16x16x32_bf16(af[mf], bf[nf],
                                                                     acc[mf][nf], 0, 0, 0);
    }

    const int rl = lane & 15;
    const int rg = lane >> 4;
    #pragma unroll
    for (int nf = 0; nf < 4; ++nf) {
        int n = wn * 64 + nf * 16 + rl;
        float bb = FIRST ? bias[n] : 0.0f;
        #pragma unroll
        for (int mf = 0; mf < 2; ++mf) {
            #pragma unroll
            for (int i = 0; i < 4; ++i) {
                int nd = nd0 + wm * 32 + mf * 16 + rg * 4 + i;
                if (nd < N) {
                    size_t o = (size_t)nd * 128 + n;
                    if (FIRST) out[o] = acc[mf][nf][i] + bb;
                    else       out[o] += acc[mf][nf][i];
                }
            }
        }
    }
}

extern "C" void kernel_launch(void* const* d_in, const int* in_sizes, int n_in,
                              void* d_out, int out_size, void* d_ws, size_t ws_size,
                              hipStream_t stream) {
    const float* x     = (const float*)d_in[0];
    const float* W     = (const float*)d_in[1];
    const float* Wroot = (const float*)d_in[2];
    const float* bias  = (const float*)d_in[3];
    const int*   ei    = (const int*)d_in[4];
    const int*   et    = (const int*)d_in[5];
    float*       out   = (float*)d_out;

    const int N = in_sizes[0] / D;
    const int E = in_sizes[5];
    const int* src = ei;
    const int* dst = ei + E;

    const int NSEG = N * R;
    const int NB   = (NSEG + 256) / 256;

    const size_t mean_bytes   = (size_t)NSEG * CW * 2;     // 102.4 MB
    const size_t xbf_bytes    = (size_t)N * D * 2;         // 25.6 MB
    const size_t walltc_bytes = (size_t)128 * 640 * 2;     // max KW=640
    const size_t need = mean_bytes + xbf_bytes + walltc_bytes +
                        ((size_t)(NSEG + 1) + NSEG + E + NB + 32 + 2 * (size_t)E) * 4 + 256;
    if (ws_size < need) return;

    char* p = (char*)d_ws;
    unsigned short* mean   = (unsigned short*)p;  p += mean_bytes;
    unsigned short* xbf    = (unsigned short*)p;  p += xbf_bytes;
    unsigned short* WallTc = (unsigned short*)p;  p += walltc_bytes;
    int* hstart   = (int*)p;  p += (size_t)(NSEG + 1) * 4;
    int* cursor   = (int*)p;  p += (size_t)NSEG * 4;
    int* spack    = (int*)p;  p += (size_t)E * 4;
    int* bsum     = (int*)p;  p += (size_t)NB * 4;
    int* meta     = (int*)p;  p += 32 * 4;
    int* ebuf_seg = (int*)p;  p += (size_t)E * 4;
    int* ebuf_src = (int*)p;

    hipMemsetAsync(hstart, 0, (size_t)(NSEG + 1) * 4, stream);
    hipMemsetAsync(meta, 0, 32 * 4, stream);

    xbf_kernel<<<2048, 256, 0, stream>>>(x, xbf, N * D / 4);

    bcount_kernel<<<1024, 256, 0, stream>>>(dst, et, meta, hstart, E);
    bscan_kernel<<<1, 64, 0, stream>>>(meta);
    bucketA_kernel<<<(E + TILE - 1) / TILE, 256, 0, stream>>>(
        src, dst, et, ebuf_seg, ebuf_src, meta, E);
    block_sums_kernel<<<NB, 256, 0, stream>>>(hstart, bsum, NSEG);
    scan_bsum_kernel<<<1, 64, 0, stream>>>(bsum, NB);
    scan_block_kernel<<<NB, 256, 0, stream>>>(hstart, bsum, cursor, NSEG, E);
    bucketB_kernel<<<768, 256, 0, stream>>>(ebuf_seg, ebuf_src, meta, cursor, spack);

    const int gx = (N + 63) / 64;
    for (int c = 0; c < 2; ++c) {
        int c0    = c * CW;
        int first = (c == 0);
        aggregate_kernel<<<(NSEG * 8 + 255) / 256, 256, 0, stream>>>(
            xbf, spack, hstart, mean, NSEG, c0);
        int KW   = (first ? 128 : 0) + R * CW;   // 640 / 512
        int NT   = KW / 32;
        int MROW = R * CW;                        // 512
        wallt_kernel<<<(128 * KW + 255) / 256, 256, 0, stream>>>(
            Wroot, W, WallTc, KW, c0, first);
        if (first)
            mfma_gemm_kernel<true><<<gx, 256, 0, stream>>>(
                xbf, mean, WallTc, bias, out, N, NT, KW, MROW);
        else
            mfma_gemm_kernel<false><<<gx, 256, 0, stream>>>(
                xbf, mean, WallTc, bias, out, N, NT, KW, MROW);
    }
}